// Round 1
// baseline (33.576 us; speedup 1.0000x reference)
//
#include <hip/hip_runtime.h>

typedef unsigned long long u64;
typedef unsigned int u32;

#define HW 65536          // 256*256 attention positions per batch
#define NSPLIT 64         // scan blocks per batch
#define CHUNK (HW / NSPLIT)   // 1024 elements per scan block
#define PERLANE (CHUNK / 64)  // 16 elements per lane
#define NSEL 16           // top-k
#define NB 8              // batch
#define NPATCH 16
#define NC 3
#define HH 2048           // x_high H=W
#define PATCHSZ 128

// map f32 to order-preserving u32 (bigger float <-> bigger uint)
__device__ __forceinline__ u32 f2o(float f) {
  u32 u = __float_as_uint(f);
  return (u & 0x80000000u) ? ~u : (u | 0x80000000u);
}

// all-lanes wave max of u64 via shfl_xor butterfly (wave = 64)
__device__ __forceinline__ u64 wave_max64(u64 k) {
#pragma unroll
  for (int off = 1; off < 64; off <<= 1) {
    u32 lo = __shfl_xor((u32)k, off, 64);
    u32 hi = __shfl_xor((u32)(k >> 32), off, 64);
    u64 o = ((u64)hi << 32) | lo;
    if (o > k) k = o;
  }
  return k;
}

// Stage 1: each 64-thread block scans CHUNK elements of one batch,
// emits its sorted top-16 keys (u64: value-desc, index-asc) to ws.
__global__ __launch_bounds__(64) void scan_topk(
    const float* __restrict__ att, const float* __restrict__ noise,
    u64* __restrict__ cand) {
  const int blk = blockIdx.x;            // b * NSPLIT + s
  const int b = blk >> 6;                // / NSPLIT
  const int s = blk & (NSPLIT - 1);
  const int lane = threadIdx.x;
  const int ebase = s * CHUNK;
  const float* ab = att + b * HW + ebase;
  const float* nb = noise + b * HW + ebase;

  u64 keys[NSEL];
#pragma unroll
  for (int i = 0; i < NSEL; i++) keys[i] = 0ULL;

#pragma unroll
  for (int k = 0; k < PERLANE; k++) {
    const int off = lane + (k << 6);     // coalesced: consecutive lanes -> consecutive addrs
    float a = ab[off];
    float u = nb[off];
    // key = log(att) + gumbel = log(a) - log(-log(u))
    float key = logf(a) - logf(-logf(u));
    u32 e = (u32)(ebase + off);
    u64 kk = ((u64)f2o(key) << 32) | (0xFFFFFFFFu - e);
    // statically-unrolled bubble insert into descending sorted list
#pragma unroll
    for (int i = 0; i < NSEL; i++) {
      if (kk > keys[i]) { u64 t = keys[i]; keys[i] = kk; kk = t; }
    }
  }

  // 16 rounds of wave argmax over per-lane sorted heads
  u64 won = 0ULL;
#pragma unroll
  for (int r = 0; r < NSEL; r++) {
    u64 g = wave_max64(keys[0]);
    if (lane == r) won = g;              // lane r records round-r winner
    if (keys[0] == g) {                  // unique keys -> exactly one lane matches
#pragma unroll
      for (int i = 0; i < NSEL - 1; i++) keys[i] = keys[i + 1];
      keys[NSEL - 1] = 0ULL;
    }
  }
  if (lane < NSEL) cand[blk * NSEL + lane] = won;
}

// Stage 2: one wave per batch merges NSPLIT*16 = 1024 candidates -> final top-16.
// Writes selected flat indices (ws) and sampled_attention (tail of d_out).
__global__ __launch_bounds__(64) void merge_topk(
    const u64* __restrict__ cand, const float* __restrict__ att,
    int* __restrict__ idx_sel, float* __restrict__ att_out) {
  const int b = blockIdx.x;
  const int lane = threadIdx.x;
  const u64* cb = cand + b * (NSPLIT * NSEL);   // 1024 candidates

  u64 keys[NSEL];
#pragma unroll
  for (int i = 0; i < NSEL; i++) keys[i] = 0ULL;

#pragma unroll
  for (int k = 0; k < 16; k++) {
    u64 kk = cb[lane + (k << 6)];
#pragma unroll
    for (int i = 0; i < NSEL; i++) {
      if (kk > keys[i]) { u64 t = keys[i]; keys[i] = kk; kk = t; }
    }
  }

  u64 won = 0ULL;
#pragma unroll
  for (int r = 0; r < NSEL; r++) {
    u64 g = wave_max64(keys[0]);
    if (lane == r) won = g;
    if (keys[0] == g) {
#pragma unroll
      for (int i = 0; i < NSEL - 1; i++) keys[i] = keys[i + 1];
      keys[NSEL - 1] = 0ULL;
    }
  }
  if (lane < NSEL) {
    u32 e = 0xFFFFFFFFu - (u32)(won & 0xFFFFFFFFu);
    idx_sel[b * NSEL + lane] = (int)e;
    att_out[b * NSEL + lane] = att[b * HW + (int)e];   // bit-exact gather
  }
}

// Stage 3: zero-padded 128x128 patch copy. One block per (b,n,c,half-patch):
// 768 blocks (exactly 3 per CU) x 256 threads, float4 rows.
__global__ __launch_bounds__(256) void patch_extract(
    const float* __restrict__ xh, const int* __restrict__ idx_sel,
    float* __restrict__ out) {
  const int blk = blockIdx.x;       // [0, 768)
  const int h = blk & 1;            // top/bottom half (64 rows each)
  const int pairc = blk >> 1;       // (b*16+n)*3 + c
  const int c = pairc % 3;
  const int bn = pairc / 3;         // b*16 + n
  const int b = bn >> 4;
  const int e = idx_sel[bn];
  const int sr = e >> 8;            // idx / 256
  const int sc = e & 255;           // idx % 256
  const int r0 = sr * 8 - 60 + h * 64;   // unpadded row start for this half
  const int c0 = sc * 8 - 60;            // unpadded col start (multiple of 4)
  const float* src = xh + ((size_t)(b * NC + c) << 22);   // 2048*2048 = 1<<22
  float* dst = out + (size_t)pairc * (PATCHSZ * PATCHSZ) + (size_t)h * (64 * PATCHSZ);

#pragma unroll
  for (int i = threadIdx.x; i < 64 * 32; i += 256) {  // 2048 float4 per half-patch
    const int pr = i >> 5;          // row within half 0..63
    const int q = i & 31;           // float4 index within row
    const int r = r0 + pr;
    const int cc = c0 + (q << 2);
    float4 v = make_float4(0.f, 0.f, 0.f, 0.f);
    // cc is a multiple of 4, so a float4 group is fully in-bounds or fully out
    if ((u32)r < (u32)HH && (u32)cc < (u32)HH) {
      v = *reinterpret_cast<const float4*>(src + ((size_t)r << 11) + cc);
    }
    *reinterpret_cast<float4*>(dst + ((size_t)i << 2)) = v;
  }
}

extern "C" void kernel_launch(void* const* d_in, const int* in_sizes, int n_in,
                              void* d_out, int out_size, void* d_ws, size_t ws_size,
                              hipStream_t stream) {
  (void)in_sizes; (void)n_in; (void)out_size; (void)ws_size;
  // inputs: 0=x_low (unused, shape-only), 1=x_high, 2=attention, 3=noise_u
  const float* x_high = (const float*)d_in[1];
  const float* att    = (const float*)d_in[2];
  const float* noise  = (const float*)d_in[3];
  float* out = (float*)d_out;
  float* att_out = out + (size_t)NB * NPATCH * NC * PATCHSZ * PATCHSZ;  // 6291456

  u64* cand   = (u64*)d_ws;                                        // 8*64*16*8 = 64 KiB
  int* idx_sel = (int*)((char*)d_ws + (size_t)NB * NSPLIT * NSEL * sizeof(u64));

  scan_topk<<<NB * NSPLIT, 64, 0, stream>>>(att, noise, cand);
  merge_topk<<<NB, 64, 0, stream>>>(cand, att, idx_sel, att_out);
  patch_extract<<<NB * NPATCH * NC * 2, 256, 0, stream>>>(x_high, idx_sel, out);
}

// Round 2
// 33.076 us; speedup vs baseline: 1.0151x; 1.0151x over previous
//
#include <hip/hip_runtime.h>

typedef unsigned long long u64;
typedef unsigned int u32;

#define HW 65536            // 256*256 attention positions per batch
#define NB 8                // batch
#define NSEL 16             // top-k
#define NPATCH 16
#define NC 3
#define HH 2048             // x_high H=W
#define PATCHSZ 128
#define NCHUNK 256          // 256-element chunks per batch (one wave each)
#define CAP 1024            // candidate buffer per batch

// surrogate key: order(log a - log(-log u)) == order(a / (-log2 u)).
// MUST be the single shared definition so both passes compute bit-identical w.
__device__ __forceinline__ u32 wkey(float a, float u) {
  float v = __builtin_amdgcn_logf(u);            // log2(u) < 0
  float w = a * __builtin_amdgcn_rcpf(-v);       // a / (-log2 u) > 0
  return __float_as_uint(w);                     // positive floats order as uints
}

__device__ __forceinline__ u32 wave_max_u32(u32 k) {
#pragma unroll
  for (int off = 1; off < 64; off <<= 1) {
    u32 o = __shfl_xor(k, off, 64);
    k = (o > k) ? o : k;
  }
  return k;
}

__device__ __forceinline__ u64 wave_max64(u64 k) {
#pragma unroll
  for (int off = 1; off < 64; off <<= 1) {
    u32 lo = __shfl_xor((u32)k, off, 64);
    u32 hi = __shfl_xor((u32)(k >> 32), off, 64);
    u64 o = ((u64)hi << 32) | lo;
    if (o > k) k = o;
  }
  return k;
}

// Stage 1: per-256-element-chunk max of w. 512 blocks x 256 thr (2048 waves).
// Also zeroes the per-batch candidate counters.
__global__ __launch_bounds__(256) void scan_max(
    const float* __restrict__ att, const float* __restrict__ noise,
    u32* __restrict__ cmax, u32* __restrict__ cnt) {
  const int b = blockIdx.x >> 6;
  const int blk = blockIdx.x & 63;           // 64 blocks/batch, 1024 elems each
  const int wave = threadIdx.x >> 6;
  const int lane = threadIdx.x & 63;
  const int base = b * HW + blk * 1024 + wave * 256;

  u32 best = 0;
#pragma unroll
  for (int k = 0; k < 4; k++) {
    const int i = base + (k << 6) + lane;    // coalesced
    best = max(best, wkey(att[i], noise[i]));
  }
  best = wave_max_u32(best);
  if (lane == 0) cmax[b * NCHUNK + (blk << 2) + wave] = best;
  if (blockIdx.x == 0 && threadIdx.x < NB) cnt[threadIdx.x] = 0;
}

// Stage 2: threshold T = 16th-largest chunk max (provably <= global #16),
// filter all elements, append survivors (u64 key) to per-batch list.
__global__ __launch_bounds__(256) void filter(
    const float* __restrict__ att, const float* __restrict__ noise,
    const u32* __restrict__ cmax, u32* __restrict__ cnt,
    u64* __restrict__ cand) {
  const int b = blockIdx.x >> 6;
  const int blk = blockIdx.x & 63;
  const int lane = threadIdx.x & 63;

  // every wave redundantly reduces the 256 chunk-maxes -> T (no LDS/sync)
  u32 k4[4];
#pragma unroll
  for (int j = 0; j < 4; j++) {
    u32 v = cmax[b * NCHUNK + (j << 6) + lane];
    // sorted descending insert into k4[0..j]
    k4[j] = v;
#pragma unroll
    for (int i = 3; i > 0; i--) {
      if (i <= j && k4[i] > k4[i - 1]) { u32 t = k4[i - 1]; k4[i - 1] = k4[i]; k4[i] = t; }
    }
  }
  u32 T = 0;
#pragma unroll
  for (int r = 0; r < NSEL; r++) {
    u32 g = wave_max_u32(k4[0]);
    T = g;
    if (k4[0] == g) { k4[0] = k4[1]; k4[1] = k4[2]; k4[2] = k4[3]; k4[3] = 0; }
  }

  const int ebase = b * HW + blk * 1024;
#pragma unroll
  for (int k = 0; k < 4; k++) {
    const int off = blk * 1024 + (k << 8) + threadIdx.x;
    const int i = b * HW + (off - blk * 1024) + blk * 1024;  // = b*HW + off
    (void)i;
    const int gi = ebase + (k << 8) + threadIdx.x;
    u32 w = wkey(att[gi], noise[gi]);
    if (w >= T) {
      u32 pos = atomicAdd(&cnt[b], 1u);
      if (pos < CAP) {
        u32 e = (u32)(gi - b * HW);
        cand[b * CAP + pos] = ((u64)w << 32) | (0xFFFFFFFFu - e);
      }
    }
  }
}

// Stage 3: one wave per batch: exact top-16 of the ~20-30 candidates.
__global__ __launch_bounds__(64) void final_topk(
    const u64* __restrict__ cand, const u32* __restrict__ cnt,
    const float* __restrict__ att, int* __restrict__ idx_sel,
    float* __restrict__ att_out) {
  const int b = blockIdx.x;
  const int lane = threadIdx.x;
  int n = (int)cnt[b]; if (n > CAP) n = CAP;

  u64 keys[NSEL];
#pragma unroll
  for (int i = 0; i < NSEL; i++) keys[i] = 0ULL;
  for (int i = lane; i < n; i += 64) {
    u64 kk = cand[b * CAP + i];
#pragma unroll
    for (int j = 0; j < NSEL; j++) {
      if (kk > keys[j]) { u64 t = keys[j]; keys[j] = kk; kk = t; }
    }
  }

  u64 won = 0ULL;
#pragma unroll
  for (int r = 0; r < NSEL; r++) {
    u64 g = wave_max64(keys[0]);
    if (lane == r) won = g;
    if (keys[0] == g) {
#pragma unroll
      for (int i = 0; i < NSEL - 1; i++) keys[i] = keys[i + 1];
      keys[NSEL - 1] = 0ULL;
    }
  }
  if (lane < NSEL) {
    u32 e = 0xFFFFFFFFu - (u32)(won & 0xFFFFFFFFu);
    idx_sel[b * NSEL + lane] = (int)e;
    att_out[b * NSEL + lane] = att[b * HW + (int)e];   // bit-exact gather
  }
}

// Stage 4: zero-padded 128x128 patch copy, float4 rows. 768 blocks x 256 thr.
__global__ __launch_bounds__(256) void patch_extract(
    const float* __restrict__ xh, const int* __restrict__ idx_sel,
    float* __restrict__ out) {
  const int blk = blockIdx.x;       // [0, 768)
  const int h = blk & 1;            // top/bottom half (64 rows each)
  const int pairc = blk >> 1;       // (b*16+n)*3 + c
  const int c = pairc % 3;
  const int bn = pairc / 3;         // b*16 + n
  const int b = bn >> 4;
  const int e = idx_sel[bn];
  const int sr = e >> 8;            // idx / 256
  const int sc = e & 255;           // idx % 256
  const int r0 = sr * 8 - 60 + h * 64;   // unpadded row start for this half
  const int c0 = sc * 8 - 60;            // unpadded col start (multiple of 4)
  const float* src = xh + ((size_t)(b * NC + c) << 22);   // 2048*2048 = 1<<22
  float* dst = out + (size_t)pairc * (PATCHSZ * PATCHSZ) + (size_t)h * (64 * PATCHSZ);

#pragma unroll
  for (int i = threadIdx.x; i < 64 * 32; i += 256) {  // 2048 float4 per half-patch
    const int pr = i >> 5;          // row within half 0..63
    const int q = i & 31;           // float4 index within row
    const int r = r0 + pr;
    const int cc = c0 + (q << 2);
    float4 v = make_float4(0.f, 0.f, 0.f, 0.f);
    // cc is a multiple of 4, so a float4 group is fully in-bounds or fully out
    if ((u32)r < (u32)HH && (u32)cc < (u32)HH) {
      v = *reinterpret_cast<const float4*>(src + ((size_t)r << 11) + cc);
    }
    *reinterpret_cast<float4*>(dst + ((size_t)i << 2)) = v;
  }
}

extern "C" void kernel_launch(void* const* d_in, const int* in_sizes, int n_in,
                              void* d_out, int out_size, void* d_ws, size_t ws_size,
                              hipStream_t stream) {
  (void)in_sizes; (void)n_in; (void)out_size; (void)ws_size;
  // inputs: 0=x_low (unused, shape-only), 1=x_high, 2=attention, 3=noise_u
  const float* x_high = (const float*)d_in[1];
  const float* att    = (const float*)d_in[2];
  const float* noise  = (const float*)d_in[3];
  float* out = (float*)d_out;
  float* att_out = out + (size_t)NB * NPATCH * NC * PATCHSZ * PATCHSZ;  // 6291456

  char* ws = (char*)d_ws;
  u32* cmax    = (u32*)ws;                                   // 8*256*4 = 8 KiB
  u32* cnt     = (u32*)(ws + 8 * NCHUNK * 4);                // 8 u32
  u64* cand    = (u64*)(ws + 8 * NCHUNK * 4 + 256);          // 8*1024*8 = 64 KiB (aligned)
  int* idx_sel = (int*)(ws + 8 * NCHUNK * 4 + 256 + (size_t)NB * CAP * 8);

  scan_max<<<NB * 64, 256, 0, stream>>>(att, noise, cmax, cnt);
  filter<<<NB * 64, 256, 0, stream>>>(att, noise, cmax, cnt, cand);
  final_topk<<<NB, 64, 0, stream>>>(cand, cnt, att, idx_sel, att_out);
  patch_extract<<<NB * NPATCH * NC * 2, 256, 0, stream>>>(x_high, idx_sel, out);
}